// Round 2
// baseline (402.318 us; speedup 1.0000x reference)
//
#include <hip/hip_runtime.h>
#include <hip/hip_bf16.h>
#include <math.h>

// Problem constants (B, D, H, W, K) = (32, 256, 64, 64, 64); N = H*W = 4096
#define BB 32
#define DD 256
#define NN 4096
#define KK 64
#define EPSV 1e-8f

// ---------- helpers: manual bf16 pack/unpack (RNE), deterministic ----------
__device__ __forceinline__ unsigned int bf16pair(float a, float b) {
    unsigned int ua = __float_as_uint(a);
    unsigned int ub = __float_as_uint(b);
    ua += 0x7fffu + ((ua >> 16) & 1u);
    ub += 0x7fffu + ((ub >> 16) & 1u);
    return (ua >> 16) | (ub & 0xffff0000u);
}

// ---------- K0: reciprocal codeword norms ----------
__global__ void k_cnorm(const float* __restrict__ C, float* __restrict__ rcn) {
    int k = threadIdx.x;  // 64 threads, one per codeword
    const float4* c4 = (const float4*)(C + k * DD);
    float ss = 0.f;
#pragma unroll 8
    for (int i = 0; i < DD / 4; i++) {
        float4 v = c4[i];
        ss = fmaf(v.x, v.x, ss);
        ss = fmaf(v.y, v.y, ss);
        ss = fmaf(v.z, v.z, ss);
        ss = fmaf(v.w, v.w, ss);
    }
    rcn[k] = 1.f / fmaxf(sqrtf(ss), EPSV);
}

// ---------- K1: L = cosine sims, softmax over k, A -> bf16 workspace ----------
// grid: 512 blocks (32 b x 16 chunks of 256 n), 256 threads, thread owns one n.
__global__ __launch_bounds__(256) void k_softmax(const float* __restrict__ X,
                                                 const float* __restrict__ C,
                                                 const float* __restrict__ rcn,
                                                 unsigned int* __restrict__ A) {
    __shared__ float cn[KK * DD];  // 64 KiB: normalized codewords, [k][d]
    int t = threadIdx.x;
    // stage Cn = C * rcn[k] into LDS (coalesced float4)
#pragma unroll
    for (int i = 0; i < 16; i++) {
        int j = i * 1024 + t * 4;  // element index
        float4 v = *(const float4*)(C + j);
        float r = rcn[j >> 8];
        v.x *= r; v.y *= r; v.z *= r; v.w *= r;
        *(float4*)(cn + j) = v;
    }
    __syncthreads();

    int b = blockIdx.x >> 4;
    int n = ((blockIdx.x & 15) << 8) + t;
    const float* xp = X + (size_t)b * (DD * NN) + n;  // stride NN per d

    float L[KK];
#pragma unroll
    for (int k = 0; k < KK; k++) L[k] = 0.f;
    float ss = 0.f;

    for (int d0 = 0; d0 < DD; d0 += 16) {
        float x[16];
#pragma unroll
        for (int i = 0; i < 16; i++) x[i] = xp[(size_t)(d0 + i) * NN];
#pragma unroll
        for (int i = 0; i < 16; i++) ss = fmaf(x[i], x[i], ss);
#pragma unroll
        for (int k = 0; k < KK; k++) {
            const float4* cp = (const float4*)(cn + k * DD + d0);
#pragma unroll
            for (int q = 0; q < 4; q++) {
                float4 c = cp[q];  // wave-uniform LDS broadcast read
                L[k] = fmaf(x[q * 4 + 0], c.x, L[k]);
                L[k] = fmaf(x[q * 4 + 1], c.y, L[k]);
                L[k] = fmaf(x[q * 4 + 2], c.z, L[k]);
                L[k] = fmaf(x[q * 4 + 3], c.w, L[k]);
            }
        }
    }

    float rn = 1.f / fmaxf(sqrtf(ss), EPSV);
    float m = -1e30f;
#pragma unroll
    for (int k = 0; k < KK; k++) {
        L[k] *= rn;
        m = fmaxf(m, L[k]);
    }
    float s = 0.f;
#pragma unroll
    for (int k = 0; k < KK; k++) {
        L[k] = __expf(L[k] - m);
        s += L[k];
    }
    float inv = 1.f / s;

    // pack 64 A-values to bf16 pairs, store 128B contiguous per thread
    unsigned int up[32];
#pragma unroll
    for (int k = 0; k < KK; k += 2) up[k >> 1] = bf16pair(L[k] * inv, L[k + 1] * inv);
    int4* dst = (int4*)(A + ((size_t)b * NN + n) * (KK / 2));
#pragma unroll
    for (int j = 0; j < 8; j++)
        dst[j] = make_int4(up[j * 4 + 0], up[j * 4 + 1], up[j * 4 + 2], up[j * 4 + 3]);
}

// ---------- K2: aggregation GEMM E_partial[k][d] = sum_n A[n][k] * X[n][d] ----------
// grid: 256 blocks (32 b x 8 chunks of 512 n), 256 threads.
// thread (kq = t&15, dg = t>>4) owns k = kq*4..kq*4+3, d = dg*16..dg*16+15.
template <bool PARTIALS>
__global__ __launch_bounds__(256) void k_agg(const float* __restrict__ X,
                                             const unsigned int* __restrict__ A,
                                             float* __restrict__ P_or_out,
                                             float* __restrict__ Sp) {
    __shared__ float xt[64 * 260];          // 66,560 B  X subtile [n][d], stride 260
    __shared__ unsigned int at[64 * 32];    // 8,192 B   A subtile [n][k-pairs]
    __shared__ float s_lds[KK];

    int t = threadIdx.x;
    int b = blockIdx.x >> 3;
    int chunk = blockIdx.x & 7;
    int kq = t & 15;
    int dg = t >> 4;

    float acc[4][16];
#pragma unroll
    for (int i = 0; i < 4; i++)
#pragma unroll
        for (int j = 0; j < 16; j++) acc[i][j] = 0.f;
    float accs[4] = {0.f, 0.f, 0.f, 0.f};

    for (int sub = 0; sub < 8; sub++) {
        int n0 = chunk * 512 + sub * 64;
        __syncthreads();  // previous subtile fully consumed
        // stage A subtile: 8 KiB contiguous
        {
            const int4* src = (const int4*)(A + ((size_t)b * NN + n0) * (KK / 2));
            int4* d4 = (int4*)at;
            d4[t] = src[t];
            d4[t + 256] = src[t + 256];
        }
        // stage X subtile: coalesced (64 consecutive n per instruction)
        {
            int nl = t & 63;
            int dbase = t >> 6;  // 0..3
            const float* xg = X + (size_t)b * (DD * NN) + n0 + nl;
#pragma unroll 8
            for (int i = 0; i < 64; i++) {
                int d = dbase + i * 4;
                xt[nl * 260 + d] = xg[(size_t)d * NN];
            }
        }
        __syncthreads();

#pragma unroll 4
        for (int n = 0; n < 64; n++) {
            const uint2* ap = (const uint2*)(at + n * 32 + kq * 2);
            uint2 u = *ap;  // 4 bf16 A-values for this thread's k's
            float a0 = __uint_as_float(u.x << 16);
            float a1 = __uint_as_float(u.x & 0xffff0000u);
            float a2 = __uint_as_float(u.y << 16);
            float a3 = __uint_as_float(u.y & 0xffff0000u);
            accs[0] += a0; accs[1] += a1; accs[2] += a2; accs[3] += a3;
            const float4* xp4 = (const float4*)(xt + n * 260 + dg * 16);
            float4 xv0 = xp4[0], xv1 = xp4[1], xv2 = xp4[2], xv3 = xp4[3];
            float xr[16] = {xv0.x, xv0.y, xv0.z, xv0.w, xv1.x, xv1.y, xv1.z, xv1.w,
                            xv2.x, xv2.y, xv2.z, xv2.w, xv3.x, xv3.y, xv3.z, xv3.w};
            float av[4] = {a0, a1, a2, a3};
#pragma unroll
            for (int i = 0; i < 4; i++)
#pragma unroll
                for (int j = 0; j < 16; j++) acc[i][j] = fmaf(av[i], xr[j], acc[i][j]);
        }
    }

    __syncthreads();
    // S[k]: the 16 dg-threads sharing a kq computed IDENTICAL accs over the same
    // n-range — only dg==0 may contribute, else S is 16x overcounted (R0 bug).
    // 16 threads x 4 k = 64 distinct k -> plain store, no atomic needed.
    if (dg == 0) {
#pragma unroll
        for (int i = 0; i < 4; i++) s_lds[kq * 4 + i] = accs[i];
    }
    __syncthreads();

    if (PARTIALS) {
        float* Pw = P_or_out + (size_t)blockIdx.x * (KK * DD);
#pragma unroll
        for (int i = 0; i < 4; i++) {
            int k = kq * 4 + i;
#pragma unroll
            for (int jj = 0; jj < 4; jj++) {
                *(float4*)(Pw + k * DD + dg * 16 + jj * 4) =
                    make_float4(acc[i][jj * 4 + 0], acc[i][jj * 4 + 1],
                                acc[i][jj * 4 + 2], acc[i][jj * 4 + 3]);
            }
        }
        if (t < KK) Sp[blockIdx.x * KK + t] = s_lds[t];
    } else {
        float* ob = P_or_out + (size_t)b * (KK * DD);
#pragma unroll
        for (int i = 0; i < 4; i++) {
            int k = kq * 4 + i;
#pragma unroll
            for (int j = 0; j < 16; j++) atomicAdd(&ob[k * DD + dg * 16 + j], acc[i][j]);
        }
        if (t < KK) atomicAdd(&Sp[b * KK + t], s_lds[t]);
    }
}

// ---------- K3: finalize ----------
__global__ __launch_bounds__(256) void k_fin_partials(const float* __restrict__ P,
                                                      const float* __restrict__ Sp,
                                                      const float* __restrict__ C,
                                                      float* __restrict__ out) {
    int idx = blockIdx.x * 256 + threadIdx.x;  // 524288 total
    int d = idx & 255;
    int k = (idx >> 8) & 63;
    int b = idx >> 14;
    float e = 0.f, s = 0.f;
#pragma unroll
    for (int c = 0; c < 8; c++) {
        int wg = b * 8 + c;
        e += P[(size_t)wg * (KK * DD) + k * DD + d];
        s += Sp[wg * KK + k];
    }
    out[idx] = e - s * C[k * DD + d];
}

__global__ __launch_bounds__(256) void k_fin_atomic(const float* __restrict__ Sp,
                                                    const float* __restrict__ C,
                                                    float* __restrict__ out) {
    int idx = blockIdx.x * 256 + threadIdx.x;
    int d = idx & 255;
    int k = (idx >> 8) & 63;
    int b = idx >> 14;
    out[idx] = out[idx] - Sp[b * KK + k] * C[k * DD + d];
}

// ---------- launch ----------
extern "C" void kernel_launch(void* const* d_in, const int* in_sizes, int n_in,
                              void* d_out, int out_size, void* d_ws, size_t ws_size,
                              hipStream_t stream) {
    const float* X = (const float*)d_in[0];
    const float* C = (const float*)d_in[1];
    float* out = (float*)d_out;
    unsigned char* ws = (unsigned char*)d_ws;

    // workspace layout (bytes)
    const size_t OFF_RC = 0;                         // 256 B (64 floats)
    const size_t OFF_A = 256;                        // A bf16: B*N*K*2 = 16,777,216 B
    const size_t A_BYTES = (size_t)BB * NN * KK * 2;
    const size_t OFF_P = OFF_A + A_BYTES;            // partials: 256*64*256*4 B
    const size_t P_BYTES = (size_t)256 * KK * DD * 4;
    const size_t OFF_SP = OFF_P + P_BYTES;           // per-wg S: 256*64*4 B
    const size_t NEED_FULL = OFF_SP + (size_t)256 * KK * 4;

    float* rcn = (float*)(ws + OFF_RC);
    unsigned int* A = (unsigned int*)(ws + OFF_A);

    bool partials = ws_size >= NEED_FULL;

    k_cnorm<<<1, 64, 0, stream>>>(C, rcn);
    k_softmax<<<512, 256, 0, stream>>>(X, C, rcn, A);

    if (partials) {
        float* P = (float*)(ws + OFF_P);
        float* Sp = (float*)(ws + OFF_SP);
        k_agg<true><<<256, 256, 0, stream>>>(X, A, P, Sp);
        k_fin_partials<<<2048, 256, 0, stream>>>(P, Sp, C, out);
    } else {
        // atomic fallback: S accumulator lives at OFF_P
        float* Sp = (float*)(ws + OFF_P);
        hipMemsetAsync(out, 0, (size_t)out_size * 4, stream);
        hipMemsetAsync(Sp, 0, (size_t)BB * KK * 4, stream);
        k_agg<false><<<256, 256, 0, stream>>>(X, A, out, Sp);
        k_fin_atomic<<<2048, 256, 0, stream>>>(Sp, C, out);
    }
}

// Round 3
// 234.884 us; speedup vs baseline: 1.7128x; 1.7128x over previous
//
#include <hip/hip_runtime.h>
#include <hip/hip_bf16.h>
#include <math.h>

// (B, D, H, W, K) = (32, 256, 64, 64, 64); N = H*W = 4096
#define BB 32
#define DD 256
#define NN 4096
#define KK 64
#define EPSV 1e-8f

typedef __attribute__((ext_vector_type(8))) short short8;   // 8 bf16 (4 VGPRs)
typedef __attribute__((ext_vector_type(4))) float f32x4;

__device__ __forceinline__ unsigned int bf16pair(float a, float b) {
    unsigned int ua = __float_as_uint(a);
    unsigned int ub = __float_as_uint(b);
    ua += 0x7fffu + ((ua >> 16) & 1u);
    ub += 0x7fffu + ((ub >> 16) & 1u);
    return (ua >> 16) | (ub & 0xffff0000u);
}
__device__ __forceinline__ unsigned short bf16one(float a) {
    unsigned int ua = __float_as_uint(a);
    ua += 0x7fffu + ((ua >> 16) & 1u);
    return (unsigned short)(ua >> 16);
}

// ---------- K0: reciprocal codeword norms ----------
__global__ void k_cnorm(const float* __restrict__ C, float* __restrict__ rcn) {
    int k = threadIdx.x;  // 64 threads
    const float4* c4 = (const float4*)(C + k * DD);
    float ss = 0.f;
#pragma unroll 8
    for (int i = 0; i < DD / 4; i++) {
        float4 v = c4[i];
        ss = fmaf(v.x, v.x, ss);
        ss = fmaf(v.y, v.y, ss);
        ss = fmaf(v.z, v.z, ss);
        ss = fmaf(v.w, v.w, ss);
    }
    rcn[k] = 1.f / fmaxf(sqrtf(ss), EPSV);
}

// ---------- K1: fused  L-GEMM -> softmax -> agg-GEMM ----------
// grid 512 = 32 b x 16 n-chunks of 256; 4 passes of 64 n per block; 4 waves.
// Orientation: Lt[k][n] = Cn * X^T (MFMA, contraction d);
//              Et[d][k] = X^T * A  (MFMA, contraction n).
// All LDS tiles XOR-swizzled in 16B blocks: elem(row,col) at
//   row*C + ((col>>3 ^ (row&7))<<3) + (col&7)   -> b128 frags aligned+bank-balanced.
__global__ __launch_bounds__(256) void k_fused(const float* __restrict__ X,
                                               const float* __restrict__ C,
                                               const float* __restrict__ rcn,
                                               float* __restrict__ P,
                                               float* __restrict__ Sp) {
    __shared__ unsigned short cn_s[KK * DD];   // [k][d] bf16, 32 KiB
    __shared__ unsigned short xnd_s[64 * DD];  // [n][d] bf16, 32 KiB
    __shared__ unsigned short xdn_s[DD * 64];  // [d][n] bf16, 32 KiB
    __shared__ unsigned short at_s[KK * 64];   // [k][n] bf16, 8 KiB
    __shared__ float psum[8 * 64];
    __shared__ float rn_s[64];
    __shared__ float s_red[4 * 64];

    int t = threadIdx.x;
    int b = blockIdx.x >> 4;
    int chunk = blockIdx.x & 15;
    int w = t >> 6;          // wave
    int lane = t & 63;
    int c = lane & 15;       // MFMA col / m-index
    int g = lane >> 4;       // MFMA quad
    int c7 = c & 7;

    // ---- stage normalized codewords (once per block) ----
#pragma unroll
    for (int i = 0; i < 16; i++) {
        int idx = i * 1024 + t * 4;
        int k = idx >> 8, d = idx & 255;
        float4 v = *(const float4*)(C + idx);
        float r = rcn[k];
        unsigned u0 = bf16pair(v.x * r, v.y * r);
        unsigned u1 = bf16pair(v.z * r, v.w * r);
        int us = k * DD + ((((d >> 3) ^ (k & 7)) << 3) | (d & 7));
        *(unsigned int*)(cn_s + us) = u0;
        *(unsigned int*)(cn_s + us + 2) = u1;
    }

    f32x4 eacc[4][4];  // [dtile][ktile]: Et accumulator, d-range = w*64..w*64+63
#pragma unroll
    for (int dt = 0; dt < 4; dt++)
#pragma unroll
        for (int kt = 0; kt < 4; kt++) eacc[dt][kt] = (f32x4){0.f, 0.f, 0.f, 0.f};
    float s_acc[4][4];  // [ktile][reg] per-lane partial S over this lane's n's
#pragma unroll
    for (int kt = 0; kt < 4; kt++)
#pragma unroll
        for (int r = 0; r < 4; r++) s_acc[kt][r] = 0.f;

    for (int p = 0; p < 4; p++) {
        int n0 = chunk * 256 + p * 64;
        __syncthreads();  // (A) prev-pass agg reads done; also covers cn staging on p==0

        // ---- stage X[d=0..255][n0..n0+63] -> xdn (direct) + xnd (transposed) ----
        {
            int i5 = t & 31;   // n-pair index
            int dof = t >> 5;  // 0..7
            int n2 = 2 * i5;
            int blk = i5 >> 2;
            const float* xb = X + (size_t)b * (DD * NN) + n0 + n2;
            float ss0 = 0.f, ss1 = 0.f;
#pragma unroll 8
            for (int i = 0; i < 32; i++) {
                int d = i * 8 + dof;
                float2 v = *(const float2*)(xb + (size_t)d * NN);
                ss0 = fmaf(v.x, v.x, ss0);
                ss1 = fmaf(v.y, v.y, ss1);
                unsigned u = bf16pair(v.x, v.y);
                *(unsigned int*)(xdn_s + d * 64 + (((blk ^ (d & 7)) << 3) | (n2 & 7))) = u;
                int db = d >> 3, d7 = d & 7;
                xnd_s[n2 * DD + (((db ^ (n2 & 7)) << 3) | d7)] = (unsigned short)(u & 0xffffu);
                xnd_s[(n2 + 1) * DD + (((db ^ ((n2 + 1) & 7)) << 3) | d7)] = (unsigned short)(u >> 16);
            }
            psum[dof * 64 + n2] = ss0;
            psum[dof * 64 + n2 + 1] = ss1;
        }
        __syncthreads();  // (B) staging visible

        if (t < 64) {  // row norms from fp32 sums
            float ss = 0.f;
#pragma unroll
            for (int j = 0; j < 8; j++) ss += psum[j * 64 + t];
            rn_s[t] = 1.f / fmaxf(sqrtf(ss), EPSV);
        }

        // ---- L-GEMM: wave w computes Lt[64k][16n] for n-tile w ----
        short8 bfr[8];
        {
            const unsigned short* xr = xnd_s + (w * 16 + c) * DD;
#pragma unroll
            for (int ks = 0; ks < 8; ks++)
                bfr[ks] = *(const short8*)(xr + ((((ks << 2) + g) ^ c7) << 3));
        }
        f32x4 lacc[4];
#pragma unroll
        for (int kt = 0; kt < 4; kt++) {
            lacc[kt] = (f32x4){0.f, 0.f, 0.f, 0.f};
            const unsigned short* cr = cn_s + (kt * 16 + c) * DD;
#pragma unroll
            for (int ks = 0; ks < 8; ks++) {
                short8 af = *(const short8*)(cr + ((((ks << 2) + g) ^ c7) << 3));
                lacc[kt] = __builtin_amdgcn_mfma_f32_16x16x32_bf16(af, bfr[ks], lacc[kt], 0, 0, 0);
            }
        }
        __syncthreads();  // (C) rn_s visible

        // ---- softmax over k (64 values per n); lane's n = n0 + w*16 + c ----
        {
            float rn = rn_s[w * 16 + c];
            float lv[4][4];
            float m = -1e30f;
#pragma unroll
            for (int kt = 0; kt < 4; kt++)
#pragma unroll
                for (int r = 0; r < 4; r++) {
                    lv[kt][r] = lacc[kt][r] * rn;
                    m = fmaxf(m, lv[kt][r]);
                }
            m = fmaxf(m, __shfl_xor(m, 16));  // reduce across quads (same col c)
            m = fmaxf(m, __shfl_xor(m, 32));
            float s = 0.f;
#pragma unroll
            for (int kt = 0; kt < 4; kt++)
#pragma unroll
                for (int r = 0; r < 4; r++) {
                    lv[kt][r] = __expf(lv[kt][r] - m);
                    s += lv[kt][r];
                }
            s += __shfl_xor(s, 16);
            s += __shfl_xor(s, 32);
            float inv = 1.f / s;
            int nn = w * 16 + c;
            int nb = nn >> 3, n7 = nn & 7;
#pragma unroll
            for (int kt = 0; kt < 4; kt++)
#pragma unroll
                for (int r = 0; r < 4; r++) {
                    float a = lv[kt][r] * inv;
                    s_acc[kt][r] += a;
                    int k = kt * 16 + (g << 2) + r;
                    at_s[k * 64 + (((nb ^ (k & 7)) << 3) | n7)] = bf16one(a);
                }
        }
        __syncthreads();  // (D) at_s visible

        // ---- agg-GEMM: Et[d][k] += sum_n X[n][d]*A[n][k]; wave w: d=w*64.. ----
#pragma unroll
        for (int ks2 = 0; ks2 < 2; ks2++) {
            short8 bk[4];
#pragma unroll
            for (int kt = 0; kt < 4; kt++)
                bk[kt] = *(const short8*)(at_s + (kt * 16 + c) * 64 +
                                          ((((ks2 << 2) + g) ^ c7) << 3));
#pragma unroll
            for (int dt = 0; dt < 4; dt++) {
                short8 af = *(const short8*)(xdn_s + (w * 64 + dt * 16 + c) * 64 +
                                             ((((ks2 << 2) + g) ^ c7) << 3));
#pragma unroll
                for (int kt = 0; kt < 4; kt++)
                    eacc[dt][kt] =
                        __builtin_amdgcn_mfma_f32_16x16x32_bf16(af, bk[kt], eacc[dt][kt], 0, 0, 0);
            }
        }
    }

    // ---- epilogue: S (butterfly over the 16 cols = n's, then cross-wave) ----
#pragma unroll
    for (int kt = 0; kt < 4; kt++)
#pragma unroll
        for (int r = 0; r < 4; r++) {
            float v = s_acc[kt][r];
            v += __shfl_xor(v, 1);
            v += __shfl_xor(v, 2);
            v += __shfl_xor(v, 4);
            v += __shfl_xor(v, 8);
            if (c == 0) s_red[w * 64 + kt * 16 + (g << 2) + r] = v;
        }
    __syncthreads();
    if (t < 64) Sp[blockIdx.x * 64 + t] = s_red[t] + s_red[64 + t] + s_red[128 + t] + s_red[192 + t];

    // ---- epilogue: partials P[block][d][k] (coalesced 64B per quad-group) ----
    float* Pb = P + (size_t)blockIdx.x * (DD * KK);
#pragma unroll
    for (int dt = 0; dt < 4; dt++)
#pragma unroll
        for (int kt = 0; kt < 4; kt++)
#pragma unroll
            for (int r = 0; r < 4; r++) {
                int d = w * 64 + dt * 16 + (g << 2) + r;
                Pb[d * 64 + kt * 16 + c] = eacc[dt][kt][r];
            }
}

// ---------- K2: finalize: sum 16 partials, subtract S*C ----------
__global__ __launch_bounds__(256) void k_fin(const float* __restrict__ P,
                                             const float* __restrict__ Sp,
                                             const float* __restrict__ C,
                                             float* __restrict__ out) {
    int idx = blockIdx.x * 256 + threadIdx.x;  // 524288 total
    int b = idx >> 14;
    int r = idx & 16383;
    int d = r >> 6;
    int k = r & 63;  // consecutive threads -> consecutive k: P reads coalesced
    float e = 0.f, s = 0.f;
    int base = b * 16;
#pragma unroll
    for (int cc = 0; cc < 16; cc++) {
        e += P[(size_t)(base + cc) * (DD * KK) + d * 64 + k];
        s += Sp[(base + cc) * 64 + k];
    }
    out[(size_t)(b * 64 + k) * 256 + d] = e - s * C[k * 256 + d];
}

// ---------- launch ----------
extern "C" void kernel_launch(void* const* d_in, const int* in_sizes, int n_in,
                              void* d_out, int out_size, void* d_ws, size_t ws_size,
                              hipStream_t stream) {
    const float* X = (const float*)d_in[0];
    const float* C = (const float*)d_in[1];
    float* out = (float*)d_out;
    unsigned char* ws = (unsigned char*)d_ws;

    // ws layout: rcn 256 B | Sp 512*64*4 | P 512*256*64*4  (~33.7 MB total)
    float* rcn = (float*)(ws);
    float* Sp = (float*)(ws + 256);
    float* P = (float*)(ws + 256 + 512 * KK * 4);

    k_cnorm<<<1, 64, 0, stream>>>(C, rcn);
    k_fused<<<512, 256, 0, stream>>>(X, C, rcn, P, Sp);
    k_fin<<<2048, 256, 0, stream>>>(P, Sp, C, out);
}

// Round 4
// 214.666 us; speedup vs baseline: 1.8742x; 1.0942x over previous
//
#include <hip/hip_runtime.h>
#include <hip/hip_bf16.h>
#include <math.h>

// (B, D, H, W, K) = (32, 256, 64, 64, 64); N = H*W = 4096
#define BB 32
#define DD 256
#define NN 4096
#define KK 64
#define EPSV 1e-8f
#define XSTR 264   // xnd row stride (shorts): 528 B = 16B-aligned, bank-rotating

typedef __attribute__((ext_vector_type(8))) short short8;   // 8 bf16
typedef __attribute__((ext_vector_type(4))) float f32x4;

__device__ __forceinline__ unsigned int bf16pair(float a, float b) {
    unsigned int ua = __float_as_uint(a);
    unsigned int ub = __float_as_uint(b);
    ua += 0x7fffu + ((ua >> 16) & 1u);
    ub += 0x7fffu + ((ub >> 16) & 1u);
    return (ua >> 16) | (ub & 0xffff0000u);
}
__device__ __forceinline__ unsigned short bf16one(float a) {
    unsigned int ua = __float_as_uint(a);
    ua += 0x7fffu + ((ua >> 16) & 1u);
    return (unsigned short)(ua >> 16);
}

// ---------------- fused: L-GEMM -> softmax -> agg-GEMM ----------------
// grid 512 = 32 b x 16 chunks of 256 n; 4 passes of 64 n; 4 waves, 256 thr.
// Wave w owns k-range [16w,16w+16) for the L-GEMM (Cn frags in registers)
// and d-range [64w,64w+64) for the agg-GEMM.
// LDS ~78 KB -> 2 blocks/CU (the R3 fix: was 110 KB -> 1 block/CU).
__global__ __launch_bounds__(256, 2) void k_fused(const float* __restrict__ X,
                                                  const float* __restrict__ C,
                                                  float* __restrict__ P,
                                                  float* __restrict__ Sp) {
    __shared__ unsigned short xnd_s[64 * XSTR];  // [n][d] bf16, 33792 B
    __shared__ unsigned short xdn_s[DD * 64];    // [d][n] bf16, 32768 B
    __shared__ unsigned short at_s[KK * 72];     // [k][n] bf16, 9216 B (aliased by psum)
    __shared__ float red_m[4 * 64];              // per-wave raw max  [w][n]
    __shared__ float red_s[4 * 64];              // per-wave exp-sum  [w][n]
    __shared__ float rn_s[64];                   // 1/||x_n||
    float* psum = (float*)at_s;  // [q=16][n=64] f32; dead before at_s written

    int t = threadIdx.x;
    int b = blockIdx.x >> 4, chunk = blockIdx.x & 15;
    int w = t >> 6, lane = t & 63, c = lane & 15, g = lane >> 4;
    int q = t >> 4;  // 4w + g
    int n4 = c * 4;

    // ---- codeword fragments in registers + on-the-fly row norm ----
    // cnf[ks] = Cn[k=16w+c][d = 32ks+8g .. +8]  (A-operand layout)
    short8 cnf[8];
    {
        int k = 16 * w + c;
        const float* cp = C + k * DD;
        float4 v0[8], v1[8];
        float ss = 0.f;
#pragma unroll
        for (int ks = 0; ks < 8; ks++) {
            v0[ks] = *(const float4*)(cp + 32 * ks + 8 * g);
            v1[ks] = *(const float4*)(cp + 32 * ks + 8 * g + 4);
            ss = fmaf(v0[ks].x, v0[ks].x, ss); ss = fmaf(v0[ks].y, v0[ks].y, ss);
            ss = fmaf(v0[ks].z, v0[ks].z, ss); ss = fmaf(v0[ks].w, v0[ks].w, ss);
            ss = fmaf(v1[ks].x, v1[ks].x, ss); ss = fmaf(v1[ks].y, v1[ks].y, ss);
            ss = fmaf(v1[ks].z, v1[ks].z, ss); ss = fmaf(v1[ks].w, v1[ks].w, ss);
        }
        ss += __shfl_xor(ss, 16);  // sum over g: lane's 64 d -> full 256 d
        ss += __shfl_xor(ss, 32);
        float r = 1.f / fmaxf(sqrtf(ss), EPSV);
#pragma unroll
        for (int ks = 0; ks < 8; ks++) {
            uint4 u;
            u.x = bf16pair(v0[ks].x * r, v0[ks].y * r);
            u.y = bf16pair(v0[ks].z * r, v0[ks].w * r);
            u.z = bf16pair(v1[ks].x * r, v1[ks].y * r);
            u.w = bf16pair(v1[ks].z * r, v1[ks].w * r);
            cnf[ks] = *(short8*)&u;
        }
    }

    f32x4 eacc[4][4];  // [dtile][ktile]
#pragma unroll
    for (int dt = 0; dt < 4; dt++)
#pragma unroll
        for (int kt = 0; kt < 4; kt++) eacc[dt][kt] = (f32x4){0.f, 0.f, 0.f, 0.f};
    float s_acc[4] = {0.f, 0.f, 0.f, 0.f};  // per-reg (k = 16w+4g+r) partial S

    for (int p = 0; p < 4; p++) {
        int n0 = chunk * 256 + p * 64;
        __syncthreads();  // (A) prev-pass agg reads of at_s/xdn done

        // ---- stage: 4x(4 coalesced float4 rows) -> 4x4 reg transpose ----
        // lane covers n = n4..n4+3, d = dbase..dbase+3 per iter
        {
            f32x4 ssn = (f32x4){0.f, 0.f, 0.f, 0.f};
#pragma unroll
            for (int i = 0; i < 4; i++) {
                int dbase = q * 4 + 64 * i;
                const float* xb = X + ((size_t)b * DD + dbase) * NN + n0 + n4;
                float4 r0 = *(const float4*)(xb);
                float4 r1 = *(const float4*)(xb + NN);
                float4 r2 = *(const float4*)(xb + 2 * NN);
                float4 r3 = *(const float4*)(xb + 3 * NN);
                ssn.x = fmaf(r0.x, r0.x, ssn.x); ssn.x = fmaf(r1.x, r1.x, ssn.x);
                ssn.x = fmaf(r2.x, r2.x, ssn.x); ssn.x = fmaf(r3.x, r3.x, ssn.x);
                ssn.y = fmaf(r0.y, r0.y, ssn.y); ssn.y = fmaf(r1.y, r1.y, ssn.y);
                ssn.y = fmaf(r2.y, r2.y, ssn.y); ssn.y = fmaf(r3.y, r3.y, ssn.y);
                ssn.z = fmaf(r0.z, r0.z, ssn.z); ssn.z = fmaf(r1.z, r1.z, ssn.z);
                ssn.z = fmaf(r2.z, r2.z, ssn.z); ssn.z = fmaf(r3.z, r3.z, ssn.z);
                ssn.w = fmaf(r0.w, r0.w, ssn.w); ssn.w = fmaf(r1.w, r1.w, ssn.w);
                ssn.w = fmaf(r2.w, r2.w, ssn.w); ssn.w = fmaf(r3.w, r3.w, ssn.w);
                // xdn: row d, 4 consecutive n -> b64
                const float4 rr[4] = {r0, r1, r2, r3};
#pragma unroll
                for (int j = 0; j < 4; j++) {
                    int d = dbase + j;
                    uint2 u;
                    u.x = bf16pair(rr[j].x, rr[j].y);
                    u.y = bf16pair(rr[j].z, rr[j].w);
                    int off = d * 64 + ((((n4 >> 3) ^ (d & 7)) << 3) | (n4 & 7));
                    *(uint2*)(xdn_s + off) = u;
                }
                // xnd: row n, 4 consecutive d -> b64 (register transpose)
                {
                    float col0[4] = {r0.x, r1.x, r2.x, r3.x};
                    float col1[4] = {r0.y, r1.y, r2.y, r3.y};
                    float col2[4] = {r0.z, r1.z, r2.z, r3.z};
                    float col3[4] = {r0.w, r1.w, r2.w, r3.w};
                    const float* cols[4] = {col0, col1, col2, col3};
#pragma unroll
                    for (int j = 0; j < 4; j++) {
                        int n = n4 + j;
                        const float* cl = cols[j];
                        uint2 u;
                        u.x = bf16pair(cl[0], cl[1]);
                        u.y = bf16pair(cl[2], cl[3]);
                        int blk = (dbase >> 3) ^ ((n >> 2) & 3);
                        int off = n * XSTR + (blk << 3) + (dbase & 7);
                        *(uint2*)(xnd_s + off) = u;
                    }
                }
            }
            *(f32x4*)(psum + q * 64 + n4) = ssn;
        }
        __syncthreads();  // (B) staging + psum visible

        if (t < 64) {  // row norms
            float ss = 0.f;
#pragma unroll
            for (int j = 0; j < 16; j++) ss += psum[j * 64 + t];
            rn_s[t] = 1.f / fmaxf(sqrtf(ss), EPSV);
        }

        // ---- L-GEMM: Lt[16w..16w+16 k][64 n], A from regs, B from xnd ----
        f32x4 lacc[4];
#pragma unroll
        for (int nt = 0; nt < 4; nt++) lacc[nt] = (f32x4){0.f, 0.f, 0.f, 0.f};
#pragma unroll
        for (int ks = 0; ks < 8; ks++) {
            short8 af = cnf[ks];
#pragma unroll
            for (int nt = 0; nt < 4; nt++) {
                int n = nt * 16 + c;
                short8 bf = *(const short8*)(xnd_s + n * XSTR +
                                             (((4 * ks + g) ^ ((n >> 2) & 3)) << 3));
                lacc[nt] = __builtin_amdgcn_mfma_f32_16x16x32_bf16(af, bf, lacc[nt], 0, 0, 0);
            }
        }

        // ---- softmax stage 1: per-wave raw max per n ----
#pragma unroll
        for (int nt = 0; nt < 4; nt++) {
            float m0 = fmaxf(fmaxf(lacc[nt][0], lacc[nt][1]), fmaxf(lacc[nt][2], lacc[nt][3]));
            m0 = fmaxf(m0, __shfl_xor(m0, 16));
            m0 = fmaxf(m0, __shfl_xor(m0, 32));
            if (g == 0) red_m[w * 64 + nt * 16 + c] = m0;
        }
        __syncthreads();  // (C) red_m + rn_s visible

        float lv[4][4];
#pragma unroll
        for (int nt = 0; nt < 4; nt++) {
            int n = nt * 16 + c;
            float rn = rn_s[n];
            float mr = fmaxf(fmaxf(red_m[n], red_m[64 + n]),
                             fmaxf(red_m[128 + n], red_m[192 + n]));
            float m = mr * rn;  // rn > 0: max(rn*L) = rn*max(L)
            float s = 0.f;
#pragma unroll
            for (int r = 0; r < 4; r++) {
                lv[nt][r] = __expf(lacc[nt][r] * rn - m);
                s += lv[nt][r];
            }
            s += __shfl_xor(s, 16);
            s += __shfl_xor(s, 32);
            if (g == 0) red_s[w * 64 + nt * 16 + c] = s;
        }
        __syncthreads();  // (D) red_s visible

#pragma unroll
        for (int nt = 0; nt < 4; nt++) {
            int n = nt * 16 + c;
            float denom = red_s[n] + red_s[64 + n] + red_s[128 + n] + red_s[192 + n];
            float inv = 1.f / denom;
#pragma unroll
            for (int r = 0; r < 4; r++) {
                float a = lv[nt][r] * inv;
                s_acc[r] += a;
                int k = 16 * w + 4 * g + r;
                at_s[k * 72 + ((((n >> 3) ^ (k & 7)) << 3) | (n & 7))] = bf16one(a);
            }
        }
        __syncthreads();  // (E) at_s visible

        // ---- agg-GEMM: Et[d = 64w..][k] += sum_n X[n][d] * A[n][k] ----
#pragma unroll
        for (int ks2 = 0; ks2 < 2; ks2++) {
            short8 bk[4];
#pragma unroll
            for (int kt = 0; kt < 4; kt++) {
                int k = kt * 16 + c;
                bk[kt] = *(const short8*)(at_s + k * 72 + (((4 * ks2 + g) ^ (k & 7)) << 3));
            }
#pragma unroll
            for (int dt = 0; dt < 4; dt++) {
                int d = w * 64 + dt * 16 + c;
                short8 af = *(const short8*)(xdn_s + d * 64 + (((4 * ks2 + g) ^ (d & 7)) << 3));
#pragma unroll
                for (int kt = 0; kt < 4; kt++)
                    eacc[dt][kt] =
                        __builtin_amdgcn_mfma_f32_16x16x32_bf16(af, bk[kt], eacc[dt][kt], 0, 0, 0);
            }
        }
    }

    // ---- epilogue: partials P[block][d][k] + per-block S ----
    float* Pb = P + (size_t)blockIdx.x * (DD * KK);
#pragma unroll
    for (int dt = 0; dt < 4; dt++)
#pragma unroll
        for (int kt = 0; kt < 4; kt++)
#pragma unroll
            for (int r = 0; r < 4; r++) {
                int d = w * 64 + dt * 16 + 4 * g + r;
                Pb[d * 64 + kt * 16 + c] = eacc[dt][kt][r];
            }
#pragma unroll
    for (int r = 0; r < 4; r++) {
        float v = s_acc[r];
        v += __shfl_xor(v, 1);
        v += __shfl_xor(v, 2);
        v += __shfl_xor(v, 4);
        v += __shfl_xor(v, 8);
        if (c == 0) Sp[blockIdx.x * 64 + 16 * w + 4 * g + r] = v;
    }
}

// ---------- finalize: sum 16 partials, subtract S*C ----------
__global__ __launch_bounds__(256) void k_fin(const float* __restrict__ P,
                                             const float* __restrict__ Sp,
                                             const float* __restrict__ C,
                                             float* __restrict__ out) {
    int idx = blockIdx.x * 256 + threadIdx.x;  // 524288 total
    int b = idx >> 14;
    int r = idx & 16383;
    int d = r >> 6;
    int k = r & 63;  // consecutive threads -> consecutive k: coalesced P reads
    float e = 0.f, s = 0.f;
    int base = b * 16;
#pragma unroll
    for (int cc = 0; cc < 16; cc++) {
        e += P[(size_t)(base + cc) * (DD * KK) + d * 64 + k];
        s += Sp[(base + cc) * 64 + k];
    }
    out[(size_t)(b * 64 + k) * 256 + d] = e - s * C[k * 256 + d];
}

// ---------- launch ----------
extern "C" void kernel_launch(void* const* d_in, const int* in_sizes, int n_in,
                              void* d_out, int out_size, void* d_ws, size_t ws_size,
                              hipStream_t stream) {
    const float* X = (const float*)d_in[0];
    const float* C = (const float*)d_in[1];
    float* out = (float*)d_out;
    unsigned char* ws = (unsigned char*)d_ws;

    // ws: Sp 512*64*4 = 131072 B | P 512*256*64*4 = 33554432 B
    float* Sp = (float*)ws;
    float* P = (float*)(ws + 131072);

    k_fused<<<512, 256, 0, stream>>>(X, C, P, Sp);
    k_fin<<<2048, 256, 0, stream>>>(P, Sp, C, out);
}